// Round 4
// baseline (456.724 us; speedup 1.0000x reference)
//
#include <hip/hip_runtime.h>

// ---------- types ----------
typedef __bf16 bf16x8 __attribute__((ext_vector_type(8)));
typedef float  floatx4 __attribute__((ext_vector_type(4)));
typedef unsigned short ushortx8 __attribute__((ext_vector_type(8)));
typedef unsigned short ushortx4 __attribute__((ext_vector_type(4)));
typedef unsigned short ushortx2 __attribute__((ext_vector_type(2)));

__device__ __forceinline__ float bf2f(unsigned short u) {
    return __uint_as_float(((unsigned)u) << 16);
}
__device__ __forceinline__ unsigned short f2bf(float f) {
    unsigned u = __float_as_uint(f);
    return (unsigned short)((u + 0x7FFFu + ((u >> 16) & 1u)) >> 16);
}

// ---------- conversion / CSR helpers ----------
__global__ void cvt_f32_bf16_kernel(const float* __restrict__ in,
                                    unsigned short* __restrict__ out, int n4) {
    int i = blockIdx.x * blockDim.x + threadIdx.x;
    if (i >= n4) return;
    float4 v = ((const float4*)in)[i];
    ushortx4 o;
    o[0] = f2bf(v.x); o[1] = f2bf(v.y); o[2] = f2bf(v.z); o[3] = f2bf(v.w);
    ((ushortx4*)out)[i] = o;
}

__global__ void transpose_cvt_kernel(const float* __restrict__ in,
                                     unsigned short* __restrict__ out,
                                     int K, int N) {
    int idx = blockIdx.x * blockDim.x + threadIdx.x;
    if (idx >= K * N) return;
    int k = idx / N, n = idx - k * N;
    out[n * K + k] = f2bf(in[idx]);
}

__global__ void init_head_kernel(int* __restrict__ head, int n) {
    int i = blockIdx.x * blockDim.x + threadIdx.x;
    if (i < n) head[i] = -1;
}

// two lists per dst: head[mask*Nn + dst] — halves traversal length per step
__global__ void build_list_kernel(const int* __restrict__ ei, const int* __restrict__ em,
                                  int E, int Nn,
                                  int* __restrict__ head, int* __restrict__ nxt) {
    int e = blockIdx.x * blockDim.x + threadIdx.x;
    if (e >= E) return;
    int d = ei[E + e];
    int m = em[e];
    nxt[e] = atomicExch(&head[m * Nn + d], e);
}

// ---------- GEMM: C[M,N] = A[M,K] @ B[K,N] + bias; A bf16 row-major, Bt = B^T bf16 (N x K) ----------
// DIRECT-TO-REGISTER fragment loads, no LDS in the main loop.
// Evidence: three schedules built on global_load_lds + per-K-step barriers
// (r0 drain, r2 runtime dbuf, r3 static dbuf) all measured identical ~76 us,
// MfmaUtil ~15.5% — per-CU staging ingest pinned at ~10 B/cy regardless of
// issue depth. Fits an LDS-DMA concurrency cap (~2 outstanding per wave):
// m97's 12-wave kernel got ~22 B/cy with 2/wave in flight; ours 6-8 waves ->
// ~10. Fix: the staged LDS layout was already fragment-order, i.e. each
// lane's MFMA fragment is 16 contiguous global bytes — so load fragments
// straight to VGPRs with global_load_dwordx4 (deep per-wave queues, no
// barriers, no main-loop LDS). A/B slices are read by 2 waves each, but the
// wave pairs run on the same CU at the same kt, so the 16 KB/step slices
// L1-hit. Occupancy: only a 16 KB barrier-free epilogue buffer -> reg-bound.
#define BM 128
#define BN 128

__global__ __launch_bounds__(256) void gemm_bt_bias(
    const unsigned short* __restrict__ A,    // M x K  (bf16 bits)
    const unsigned short* __restrict__ Bt,   // N x K  (bf16 bits)
    const float* __restrict__ bias,          // N (fp32)
    unsigned short* __restrict__ C,          // M x N  (bf16 bits)
    int M, int N, int K)
{
    __shared__ unsigned short Ep[8192];      // 16 KB: per-wave epilogue repack only

    const int tid  = threadIdx.x;
    const int lane = tid & 63;
    const int wave = tid >> 6;

    // XCD-aware swizzle (only for the N-split grid.x==4 case = GEMM1):
    // blocks sharing the same A-row-tile get ids differing by 8 -> same XCD (id%8).
    int bx, by;
    if (gridDim.x == 4) {
        int id = blockIdx.y * 4 + blockIdx.x;
        int full = (gridDim.y & ~7) * 4;
        if (id < full) {
            bx = (id >> 3) & 3;
            by = (id >> 5) * 8 + (id & 7);
        } else {
            int t = id - full;
            by = (gridDim.y & ~7) + (t >> 2);
            bx = t & 3;
        }
    } else {
        bx = blockIdx.x; by = blockIdx.y;
    }
    const int bM = by * BM;
    const int bN = bx * BN;
    const int wm = (wave >> 1) * 64;   // wave sub-tile origin (2x2 waves)
    const int wn = (wave & 1) * 64;
    const int q    = lane >> 4;        // 0..3
    const int mrow = lane & 15;

    // Per-lane fragment base pointers (16B-aligned: q*8 elems = 16B, row
    // stride K*2 = 1KB). Fragment af[mi] at lane l covers
    //   A[bM + ((wave>>1)*4+mi)*16 + (l&15)][kt + s*32 + (l>>4)*8 .. +7]
    const unsigned short* ap[4];
    const unsigned short* bp[4];
#pragma unroll
    for (int mi = 0; mi < 4; mi++) {
        int r = bM + ((wave >> 1) * 4 + mi) * 16 + mrow;
        if (r >= M) r = M - 1;                 // clamp: dup rows never stored
        ap[mi] = A + (size_t)r * K + q * 8;
    }
#pragma unroll
    for (int ni = 0; ni < 4; ni++) {
        int r = bN + ((wave & 1) * 4 + ni) * 16 + mrow;  // grid.x exact -> in range
        bp[ni] = Bt + (size_t)r * K + q * 8;
    }

    floatx4 acc[4][4];
#pragma unroll
    for (int i = 0; i < 4; i++)
#pragma unroll
        for (int j = 0; j < 4; j++) acc[i][j] = (floatx4)(0.0f);

    // main loop: 16 dwordx4 fragment loads (deep MLP), then 32 MFMA.
    // No barriers; compiler pipelines across iterations freely.
    for (int kt = 0; kt < K; kt += 64) {
        bf16x8 a0[4], a1[4], b0[4], b1[4];
#pragma unroll
        for (int mi = 0; mi < 4; mi++) a0[mi] = *(const bf16x8*)(ap[mi] + kt);
#pragma unroll
        for (int ni = 0; ni < 4; ni++) b0[ni] = *(const bf16x8*)(bp[ni] + kt);
#pragma unroll
        for (int mi = 0; mi < 4; mi++) a1[mi] = *(const bf16x8*)(ap[mi] + kt + 32);
#pragma unroll
        for (int ni = 0; ni < 4; ni++) b1[ni] = *(const bf16x8*)(bp[ni] + kt + 32);
#pragma unroll
        for (int mi = 0; mi < 4; mi++)
#pragma unroll
            for (int ni = 0; ni < 4; ni++)
                acc[mi][ni] = __builtin_amdgcn_mfma_f32_16x16x32_bf16(
                    a0[mi], b0[ni], acc[mi][ni], 0, 0, 0);
#pragma unroll
        for (int mi = 0; mi < 4; mi++)
#pragma unroll
            for (int ni = 0; ni < 4; ni++)
                acc[mi][ni] = __builtin_amdgcn_mfma_f32_16x16x32_bf16(
                    a1[mi], b1[ni], acc[mi][ni], 0, 0, 0);
    }

    // ---- epilogue: per-wave LDS repack -> 16B/lane coalesced stores ----
    // acc C/D layout: col = mrow, row = q*4 + r  (m89/m91-verified).
    // Ep region is private per wave; same-wave ds_write->ds_read ordering is
    // handled by compiler-inserted lgkmcnt. No barriers anywhere.
    unsigned short* lbuf = Ep + wave * 2048;   // private 4 KB per wave
    float bv[4];
#pragma unroll
    for (int ni = 0; ni < 4; ni++) bv[ni] = bias[bN + wn + ni * 16 + mrow];

#pragma unroll
    for (int p = 0; p < 2; p++) {              // pass p covers mi = 2p, 2p+1 (32 rows)
#pragma unroll
        for (int mh = 0; mh < 2; mh++) {
            int mi = 2 * p + mh;
#pragma unroll
            for (int ni = 0; ni < 4; ni++)
#pragma unroll
                for (int r = 0; r < 4; r++)
                    lbuf[(mh * 16 + q * 4 + r) * 64 + ni * 16 + mrow] =
                        f2bf(acc[mi][ni][r] + bv[ni]);
        }
#pragma unroll
        for (int i = 0; i < 4; i++) {
            int prow = i * 8 + (lane >> 3);
            int pcol = (lane & 7) * 8;
            int grow = bM + wm + p * 32 + prow;
            if (grow < M)
                *(ushortx8*)(C + (size_t)grow * N + bN + wn + pcol) =
                    *(const ushortx8*)&lbuf[prow * 64 + pcol];
        }
    }
}

// ---------- propagate step: one wave per destination node, per-mask edge list ----------
template <int VEC> struct VecT;
template <> struct VecT<8> { typedef ushortx8 type; };
template <> struct VecT<2> { typedef ushortx2 type; };

template <int VEC, bool ADD_SELF, bool RELU, bool OUT_F32>
__global__ __launch_bounds__(256) void prop_step_kernel(
    const unsigned short* __restrict__ cur,  // bf16 [Nn, F]
    void* __restrict__ outp,                 // bf16 or fp32 [Nn, F]
    const int* __restrict__ head,            // per-mask list heads (pre-offset)
    const int* __restrict__ nxt,
    const int* __restrict__ esrc,
    int Nn)
{
    typedef typename VecT<VEC>::type VT;
    const int w = blockIdx.x * 4 + (threadIdx.x >> 6);
    if (w >= Nn) return;
    const int lane = threadIdx.x & 63;
    const int F = VEC * 64;
    const size_t off = (size_t)w * F + lane * VEC;

    float acc[VEC];
    if (ADD_SELF) {
        VT v = *(const VT*)(cur + off);
#pragma unroll
        for (int i = 0; i < VEC; i++) acc[i] = bf2f(v[i]);
    } else {
#pragma unroll
        for (int i = 0; i < VEC; i++) acc[i] = 0.0f;
    }

    for (int e = head[w]; e >= 0; e = nxt[e]) {
        int s = esrc[e];
        VT v = *(const VT*)(cur + (size_t)s * F + lane * VEC);
#pragma unroll
        for (int i = 0; i < VEC; i++) acc[i] += bf2f(v[i]);
    }

#pragma unroll
    for (int i = 0; i < VEC; i++)
        if (RELU && acc[i] < 0.0f) acc[i] = 0.0f;

    if (OUT_F32) {
        float* out = (float*)outp;
        float2 o2;
#pragma unroll
        for (int i = 0; i < VEC; i += 2) {
            o2.x = acc[i]; o2.y = acc[i + 1];
            *(float2*)(out + off + i) = o2;
        }
    } else {
        VT o;
#pragma unroll
        for (int i = 0; i < VEC; i++) o[i] = f2bf(acc[i]);
        *(VT*)((unsigned short*)outp + off) = o;
    }
}

// ---------- launch ----------
extern "C" void kernel_launch(void* const* d_in, const int* in_sizes, int n_in,
                              void* d_out, int out_size, void* d_ws, size_t ws_size,
                              hipStream_t stream)
{
    const float* x  = (const float*)d_in[0];       // [Nn, 512] fp32
    const int*   ei = (const int*)d_in[1];         // [2, E] int32
    const int*   em = (const int*)d_in[2];         // [E]
    const float* W1 = (const float*)d_in[5];       // [512,512]
    const float* b1 = (const float*)d_in[6];       // [512]
    const float* W2 = (const float*)d_in[7];       // [512,128]
    const float* b2 = (const float*)d_in[8];       // [128]

    const int FIN = 512, FOUT = 128;
    const int Nn = in_sizes[0] / FIN;   // 60000
    const int E  = in_sizes[2];         // 160000

    char* ws = (char*)d_ws;
    size_t off = 0;
    auto alloc = [&](size_t bytes) -> char* {
        char* p = ws + off;
        off += (bytes + 255) & ~(size_t)255;
        return p;
    };
    unsigned short* W1t = (unsigned short*)alloc((size_t)FIN * FIN * 2);
    unsigned short* W2t = (unsigned short*)alloc((size_t)FIN * FOUT * 2);
    unsigned short* xb  = (unsigned short*)alloc((size_t)Nn * FIN * 2); // reused as A1
    unsigned short* h1  = (unsigned short*)alloc((size_t)Nn * FIN * 2); // reused as B1
    unsigned short* h2  = (unsigned short*)alloc((size_t)Nn * FOUT * 2);
    unsigned short* A2  = (unsigned short*)alloc((size_t)Nn * FOUT * 2);
    int* head = (int*)alloc((size_t)2 * Nn * 4);   // [2][Nn]
    int* nxt  = (int*)alloc((size_t)E * 4);
    unsigned short* A1 = xb;
    (void)ws_size; (void)n_in; (void)out_size;

    // 1) convert x; transpose+convert weights
    cvt_f32_bf16_kernel<<<((Nn * FIN / 4) + 255) / 256, 256, 0, stream>>>(x, xb, Nn * FIN / 4);
    transpose_cvt_kernel<<<(FIN * FIN + 255) / 256, 256, 0, stream>>>(W1, W1t, FIN, FIN);
    transpose_cvt_kernel<<<(FIN * FOUT + 255) / 256, 256, 0, stream>>>(W2, W2t, FIN, FOUT);

    // 2) per-(mask,dst) linked lists
    init_head_kernel<<<(2 * Nn + 255) / 256, 256, 0, stream>>>(head, 2 * Nn);
    build_list_kernel<<<(E + 255) / 256, 256, 0, stream>>>(ei, em, E, Nn, head, nxt);

    // 3) h1 = x @ W1 + b1
    {
        dim3 grid(FIN / BN, (Nn + BM - 1) / BM);
        gemm_bt_bias<<<grid, 256, 0, stream>>>(xb, W1t, b1, h1, Nn, FIN, FIN);
    }

    // 4) P1: A1 = S0(h1);  B1 = relu(A1 + S1(A1))
    {
        int grid = (Nn + 3) / 4;
        prop_step_kernel<8, false, false, false><<<grid, 256, 0, stream>>>(h1, A1, head,      nxt, ei, Nn);
        prop_step_kernel<8, true,  true,  false><<<grid, 256, 0, stream>>>(A1, h1, head + Nn, nxt, ei, Nn);
    }

    // 5) h2 = B1 @ W2 + b2
    {
        dim3 grid(FOUT / BN, (Nn + BM - 1) / BM);
        gemm_bt_bias<<<grid, 256, 0, stream>>>(h1, W2t, b2, h2, Nn, FOUT, FIN);
    }

    // 6) P2: A2 = S0(h2);  out = A2 + S1(A2)  (fp32)
    {
        int grid = (Nn + 3) / 4;
        prop_step_kernel<2, false, false, false><<<grid, 256, 0, stream>>>(h2, A2, head,      nxt, ei, Nn);
        prop_step_kernel<2, true,  false, true ><<<grid, 256, 0, stream>>>(A2, d_out, head + Nn, nxt, ei, Nn);
    }
}

// Round 5
// 389.676 us; speedup vs baseline: 1.1721x; 1.1721x over previous
//
#include <hip/hip_runtime.h>

// ---------- types ----------
typedef __bf16 bf16x8 __attribute__((ext_vector_type(8)));
typedef float  floatx4 __attribute__((ext_vector_type(4)));
typedef unsigned short ushortx8 __attribute__((ext_vector_type(8)));
typedef unsigned short ushortx4 __attribute__((ext_vector_type(4)));
typedef unsigned short ushortx2 __attribute__((ext_vector_type(2)));

__device__ __forceinline__ float bf2f(unsigned short u) {
    return __uint_as_float(((unsigned)u) << 16);
}
__device__ __forceinline__ unsigned short f2bf(float f) {
    unsigned u = __float_as_uint(f);
    return (unsigned short)((u + 0x7FFFu + ((u >> 16) & 1u)) >> 16);
}

// async global->LDS, 16B per lane; lds dest = wave-uniform base + lane*16
__device__ __forceinline__ void gload_lds16(const unsigned short* g, unsigned short* l) {
    __builtin_amdgcn_global_load_lds(
        (const __attribute__((address_space(1))) void*)g,
        (__attribute__((address_space(3))) void*)l, 16, 0, 0);
}

// ---------- conversion / CSR helpers ----------
__global__ void cvt_f32_bf16_kernel(const float* __restrict__ in,
                                    unsigned short* __restrict__ out, int n4) {
    int i = blockIdx.x * blockDim.x + threadIdx.x;
    if (i >= n4) return;
    float4 v = ((const float4*)in)[i];
    ushortx4 o;
    o[0] = f2bf(v.x); o[1] = f2bf(v.y); o[2] = f2bf(v.z); o[3] = f2bf(v.w);
    ((ushortx4*)out)[i] = o;
}

__global__ void transpose_cvt_kernel(const float* __restrict__ in,
                                     unsigned short* __restrict__ out,
                                     int K, int N) {
    int idx = blockIdx.x * blockDim.x + threadIdx.x;
    if (idx >= K * N) return;
    int k = idx / N, n = idx - k * N;
    out[n * K + k] = f2bf(in[idx]);
}

__global__ void init_head_kernel(int* __restrict__ head, int n) {
    int i = blockIdx.x * blockDim.x + threadIdx.x;
    if (i < n) head[i] = -1;
}

// two lists per dst: head[mask*Nn + dst] — halves traversal length per step
__global__ void build_list_kernel(const int* __restrict__ ei, const int* __restrict__ em,
                                  int E, int Nn,
                                  int* __restrict__ head, int* __restrict__ nxt) {
    int e = blockIdx.x * blockDim.x + threadIdx.x;
    if (e >= E) return;
    int d = ei[E + e];
    int m = em[e];
    nxt[e] = atomicExch(&head[m * Nn + d], e);
}

// ============================================================================
// INGEST-BOUND THEORY (r0-r4 evidence): three different schedules on the
// 128x128 tile (drain-every-step r0, runtime dbuf r2, static dbuf r3) all
// measured 76-77 us — schedule-invariant. Aggregate LDS-staging ingest =
// A*(N/BN) + B*(M/BM) = 490 MB; 490 MB / 77 us = 6.3 TB/s = the measured
// vector-path ceiling (m13). So GEMM1 is bound by staged BYTES, not by
// latency or pipelining. r4 (direct-to-reg, no LDS) regressed to 126 us on
// L1-transaction throughput — reverted.
// Fix: 256x256 tile halves ingest to 245 MB; XCD co-location of the two
// N-column blocks makes the A re-read an L2 hit.
// ============================================================================

// ---------- GEMM 256x256: C[M,N] = A @ B + bias; 8 waves (2Mx4N), BK=64 ----
__global__ __launch_bounds__(512) void gemm256_bt_bias(
    const unsigned short* __restrict__ A,    // M x K  (bf16 bits)
    const unsigned short* __restrict__ Bt,   // N x K  (bf16 bits)
    const float* __restrict__ bias,          // N (fp32)
    unsigned short* __restrict__ C,          // M x N  (bf16 bits)
    int M, int N, int K)
{
    // 32 groups x 512 shorts each (group gg = s*16 + g; s = k-half,
    // g = 16-row group): lane l holds rows g*16+(l&15), k s*32+(l>>4)*8..+7
    __shared__ unsigned short As[16384];     // 32 KB
    __shared__ unsigned short Bs[16384];     // 32 KB  (64 KB total -> 2 blk/CU)

    const int tid  = threadIdx.x;
    const int lane = tid & 63;
    const int wave = tid >> 6;               // 0..7

    // XCD swizzle for the grid.x==2 case (GEMM1): ids 16 apart per y-group of
    // 8; (y,0) at id y8*16+(y&7), (y,1) at +8 -> same XCD (id%8) -> the A-row
    // panel is fetched once per XCD-L2 and served to both column blocks.
    int bx, by;
    if (gridDim.x == 2) {
        int id = blockIdx.y * 2 + blockIdx.x;
        int full = (gridDim.y & ~7) * 2;
        if (id < full) {
            int grp = id >> 4, w = id & 15;
            bx = w >> 3;
            by = grp * 8 + (w & 7);
        } else {
            int t = id - full;
            by = (gridDim.y & ~7) + (t >> 1);
            bx = t & 1;
        }
    } else {
        bx = blockIdx.x; by = blockIdx.y;
    }
    const int bM = by * 256;
    const int bN = bx * 256;
    const int wr = wave >> 2;          // 0..1  (M-dir)
    const int wc = wave & 3;           // 0..3  (N-dir)
    const int wm = wr * 128;
    const int wn = wc * 64;
    const int q    = lane >> 4;        // 0..3
    const int mrow = lane & 15;

    // staging: wave stages A-groups {wave, wave+8, wave+16, wave+24}, B same
    const unsigned short* pA[4];
    const unsigned short* pB[4];
#pragma unroll
    for (int c = 0; c < 4; c++) {
        int gg = wave + 8 * c;
        int g = gg & 15, s = gg >> 4;
        int rA = bM + g * 16 + mrow; if (rA >= M) rA = M - 1;  // dup rows never stored
        int rB = bN + g * 16 + mrow;                           // N % 256 == 0 -> in range
        pA[c] = A  + (size_t)rA * K + s * 32 + q * 8;
        pB[c] = Bt + (size_t)rB * K + s * 32 + q * 8;
    }

    floatx4 acc[8][4];
#pragma unroll
    for (int i = 0; i < 8; i++)
#pragma unroll
        for (int j = 0; j < 4; j++) acc[i][j] = (floatx4)(0.0f);

    for (int kt = 0; kt < K; kt += 64) {
#pragma unroll
        for (int c = 0; c < 4; c++) {
            gload_lds16(pA[c] + kt, &As[(wave + 8 * c) * 512]);
            gload_lds16(pB[c] + kt, &Bs[(wave + 8 * c) * 512]);
        }
        asm volatile("s_waitcnt vmcnt(0)\n\ts_barrier" ::: "memory");

#pragma unroll
        for (int s = 0; s < 2; s++) {
            bf16x8 af[8], bfv[4];
#pragma unroll
            for (int mi = 0; mi < 8; mi++)
                af[mi] = *(const bf16x8*)&As[(s * 16 + wr * 8 + mi) * 512 + lane * 8];
#pragma unroll
            for (int ni = 0; ni < 4; ni++)
                bfv[ni] = *(const bf16x8*)&Bs[(s * 16 + wc * 4 + ni) * 512 + lane * 8];
#pragma unroll
            for (int mi = 0; mi < 8; mi++)
#pragma unroll
                for (int ni = 0; ni < 4; ni++)
                    acc[mi][ni] = __builtin_amdgcn_mfma_f32_16x16x32_bf16(
                        af[mi], bfv[ni], acc[mi][ni], 0, 0, 0);
        }
        __syncthreads();   // LDS safe to overwrite next iter (and for epilogue)
    }

    // ---- epilogue: per-wave LDS repack -> 16B/lane coalesced stores ----
    // acc C/D layout: col = mrow, row = q*4 + r  (m89/m91-verified)
    unsigned short* lbuf = As + wave * 2048;   // private 4 KB per wave (8x4KB=32KB)
    float bv[4];
#pragma unroll
    for (int ni = 0; ni < 4; ni++) bv[ni] = bias[bN + wn + ni * 16 + mrow];

#pragma unroll
    for (int p = 0; p < 4; p++) {              // pass p covers mi = 2p, 2p+1 (32 rows)
#pragma unroll
        for (int mh = 0; mh < 2; mh++) {
            int mi = 2 * p + mh;
#pragma unroll
            for (int ni = 0; ni < 4; ni++)
#pragma unroll
                for (int r = 0; r < 4; r++)
                    lbuf[(mh * 16 + q * 4 + r) * 64 + ni * 16 + mrow] =
                        f2bf(acc[mi][ni][r] + bv[ni]);
        }
#pragma unroll
        for (int i = 0; i < 4; i++) {
            int prow = i * 8 + (lane >> 3);
            int pcol = (lane & 7) * 8;
            int grow = bM + wm + p * 32 + prow;
            if (grow < M)
                *(ushortx8*)(C + (size_t)grow * N + bN + wn + pcol) =
                    *(const ushortx8*)&lbuf[prow * 64 + pcol];
        }
    }
}

// ---------- GEMM 128x128 (round-0 proven version; used for GEMM2) ----------
#define BM 128
#define BN 128
#define BK 64

__global__ __launch_bounds__(256) void gemm_bt_bias(
    const unsigned short* __restrict__ A,    // M x K  (bf16 bits)
    const unsigned short* __restrict__ Bt,   // N x K  (bf16 bits)
    const float* __restrict__ bias,          // N (fp32)
    unsigned short* __restrict__ C,          // M x N  (bf16 bits)
    int M, int N, int K)
{
    __shared__ unsigned short Sh[16384];     // 32 KB: As[16][512] + Bs[16][512]
    unsigned short (*As)[512] = (unsigned short(*)[512])Sh;
    unsigned short (*Bs)[512] = (unsigned short(*)[512])(Sh + 8192);

    const int tid  = threadIdx.x;
    const int lane = tid & 63;
    const int wave = tid >> 6;

    int bx = blockIdx.x, by = blockIdx.y;
    const int bM = by * BM;
    const int bN = bx * BN;
    const int wm = (wave >> 1) * 64;   // wave sub-tile origin (2x2 waves)
    const int wn = (wave & 1) * 64;
    const int q    = lane >> 4;        // 0..3
    const int mrow = lane & 15;

    const unsigned short* pA[4];
    const unsigned short* pB[4];
#pragma unroll
    for (int c = 0; c < 4; c++) {
        int gg = wave + 4 * c;
        int g7 = gg & 7, s = gg >> 3;
        int rA = bM + g7 * 16 + mrow; if (rA >= M) rA = M - 1;
        int rB = bN + g7 * 16 + mrow;
        pA[c] = A  + (size_t)rA * K + s * 32 + q * 8;
        pB[c] = Bt + (size_t)rB * K + s * 32 + q * 8;
    }

    floatx4 acc[4][4];
#pragma unroll
    for (int i = 0; i < 4; i++)
#pragma unroll
        for (int j = 0; j < 4; j++) acc[i][j] = (floatx4)(0.0f);

    for (int kt = 0; kt < K; kt += BK) {
#pragma unroll
        for (int c = 0; c < 4; c++) {
            gload_lds16(pA[c] + kt, &As[wave + 4 * c][0]);
            gload_lds16(pB[c] + kt, &Bs[wave + 4 * c][0]);
        }
        __syncthreads();

#pragma unroll
        for (int s = 0; s < 2; s++) {
            bf16x8 af[4], bfv[4];
#pragma unroll
            for (int mi = 0; mi < 4; mi++)
                af[mi] = *(const bf16x8*)&As[s * 8 + (wave >> 1) * 4 + mi][lane * 8];
#pragma unroll
            for (int ni = 0; ni < 4; ni++)
                bfv[ni] = *(const bf16x8*)&Bs[s * 8 + (wave & 1) * 4 + ni][lane * 8];
#pragma unroll
            for (int mi = 0; mi < 4; mi++)
#pragma unroll
                for (int ni = 0; ni < 4; ni++)
                    acc[mi][ni] = __builtin_amdgcn_mfma_f32_16x16x32_bf16(
                        af[mi], bfv[ni], acc[mi][ni], 0, 0, 0);
        }
        __syncthreads();
    }

    unsigned short* lbuf = Sh + wave * 2048;
    float bv[4];
#pragma unroll
    for (int ni = 0; ni < 4; ni++) bv[ni] = bias[bN + wn + ni * 16 + mrow];

#pragma unroll
    for (int p = 0; p < 2; p++) {
#pragma unroll
        for (int mh = 0; mh < 2; mh++) {
            int mi = 2 * p + mh;
#pragma unroll
            for (int ni = 0; ni < 4; ni++)
#pragma unroll
                for (int r = 0; r < 4; r++)
                    lbuf[(mh * 16 + q * 4 + r) * 64 + ni * 16 + mrow] =
                        f2bf(acc[mi][ni][r] + bv[ni]);
        }
#pragma unroll
        for (int i = 0; i < 4; i++) {
            int prow = i * 8 + (lane >> 3);
            int pcol = (lane & 7) * 8;
            int grow = bM + wm + p * 32 + prow;
            if (grow < M)
                *(ushortx8*)(C + (size_t)grow * N + bN + wn + pcol) =
                    *(const ushortx8*)&lbuf[prow * 64 + pcol];
        }
    }
}

// ---------- propagate step: one wave per destination node, per-mask edge list ----------
template <int VEC> struct VecT;
template <> struct VecT<8> { typedef ushortx8 type; };
template <> struct VecT<2> { typedef ushortx2 type; };

template <int VEC, bool ADD_SELF, bool RELU, bool OUT_F32>
__global__ __launch_bounds__(256) void prop_step_kernel(
    const unsigned short* __restrict__ cur,  // bf16 [Nn, F]
    void* __restrict__ outp,                 // bf16 or fp32 [Nn, F]
    const int* __restrict__ head,            // per-mask list heads (pre-offset)
    const int* __restrict__ nxt,
    const int* __restrict__ esrc,
    int Nn)
{
    typedef typename VecT<VEC>::type VT;
    const int w = blockIdx.x * 4 + (threadIdx.x >> 6);
    if (w >= Nn) return;
    const int lane = threadIdx.x & 63;
    const int F = VEC * 64;
    const size_t off = (size_t)w * F + lane * VEC;

    float acc[VEC];
    if (ADD_SELF) {
        VT v = *(const VT*)(cur + off);
#pragma unroll
        for (int i = 0; i < VEC; i++) acc[i] = bf2f(v[i]);
    } else {
#pragma unroll
        for (int i = 0; i < VEC; i++) acc[i] = 0.0f;
    }

    for (int e = head[w]; e >= 0; e = nxt[e]) {
        int s = esrc[e];
        VT v = *(const VT*)(cur + (size_t)s * F + lane * VEC);
#pragma unroll
        for (int i = 0; i < VEC; i++) acc[i] += bf2f(v[i]);
    }

#pragma unroll
    for (int i = 0; i < VEC; i++)
        if (RELU && acc[i] < 0.0f) acc[i] = 0.0f;

    if (OUT_F32) {
        float* out = (float*)outp;
        float2 o2;
#pragma unroll
        for (int i = 0; i < VEC; i += 2) {
            o2.x = acc[i]; o2.y = acc[i + 1];
            *(float2*)(out + off + i) = o2;
        }
    } else {
        VT o;
#pragma unroll
        for (int i = 0; i < VEC; i++) o[i] = f2bf(acc[i]);
        *(VT*)((unsigned short*)outp + off) = o;
    }
}

// ---------- launch ----------
extern "C" void kernel_launch(void* const* d_in, const int* in_sizes, int n_in,
                              void* d_out, int out_size, void* d_ws, size_t ws_size,
                              hipStream_t stream)
{
    const float* x  = (const float*)d_in[0];       // [Nn, 512] fp32
    const int*   ei = (const int*)d_in[1];         // [2, E] int32
    const int*   em = (const int*)d_in[2];         // [E]
    const float* W1 = (const float*)d_in[5];       // [512,512]
    const float* b1 = (const float*)d_in[6];       // [512]
    const float* W2 = (const float*)d_in[7];       // [512,128]
    const float* b2 = (const float*)d_in[8];       // [128]

    const int FIN = 512, FOUT = 128;
    const int Nn = in_sizes[0] / FIN;   // 60000
    const int E  = in_sizes[2];         // 160000

    char* ws = (char*)d_ws;
    size_t off = 0;
    auto alloc = [&](size_t bytes) -> char* {
        char* p = ws + off;
        off += (bytes + 255) & ~(size_t)255;
        return p;
    };
    unsigned short* W1t = (unsigned short*)alloc((size_t)FIN * FIN * 2);
    unsigned short* W2t = (unsigned short*)alloc((size_t)FIN * FOUT * 2);
    unsigned short* xb  = (unsigned short*)alloc((size_t)Nn * FIN * 2); // reused as A1
    unsigned short* h1  = (unsigned short*)alloc((size_t)Nn * FIN * 2); // reused as B1
    unsigned short* h2  = (unsigned short*)alloc((size_t)Nn * FOUT * 2);
    unsigned short* A2  = (unsigned short*)alloc((size_t)Nn * FOUT * 2);
    int* head = (int*)alloc((size_t)2 * Nn * 4);   // [2][Nn]
    int* nxt  = (int*)alloc((size_t)E * 4);
    unsigned short* A1 = xb;
    (void)ws_size; (void)n_in; (void)out_size;

    // 1) convert x; transpose+convert weights
    cvt_f32_bf16_kernel<<<((Nn * FIN / 4) + 255) / 256, 256, 0, stream>>>(x, xb, Nn * FIN / 4);
    transpose_cvt_kernel<<<(FIN * FIN + 255) / 256, 256, 0, stream>>>(W1, W1t, FIN, FIN);
    transpose_cvt_kernel<<<(FIN * FOUT + 255) / 256, 256, 0, stream>>>(W2, W2t, FIN, FOUT);

    // 2) per-(mask,dst) linked lists
    init_head_kernel<<<(2 * Nn + 255) / 256, 256, 0, stream>>>(head, 2 * Nn);
    build_list_kernel<<<(E + 255) / 256, 256, 0, stream>>>(ei, em, E, Nn, head, nxt);

    // 3) h1 = x @ W1 + b1   (256x256 tile: ingest 245 MB vs 490 MB at 128^2)
    {
        dim3 grid(FIN / 256, (Nn + 255) / 256);
        gemm256_bt_bias<<<grid, 512, 0, stream>>>(xb, W1t, b1, h1, Nn, FIN, FIN);
    }

    // 4) P1: A1 = S0(h1);  B1 = relu(A1 + S1(A1))
    {
        int grid = (Nn + 3) / 4;
        prop_step_kernel<8, false, false, false><<<grid, 256, 0, stream>>>(h1, A1, head,      nxt, ei, Nn);
        prop_step_kernel<8, true,  true,  false><<<grid, 256, 0, stream>>>(A1, h1, head + Nn, nxt, ei, Nn);
    }

    // 5) h2 = B1 @ W2 + b2   (128^2 proven kernel; N=128)
    {
        dim3 grid(FOUT / BN, (Nn + BM - 1) / BM);
        gemm_bt_bias<<<grid, 256, 0, stream>>>(h1, W2t, b2, h2, Nn, FOUT, FIN);
    }

    // 6) P2: A2 = S0(h2);  out = A2 + S1(A2)  (fp32)
    {
        int grid = (Nn + 3) / 4;
        prop_step_kernel<2, false, false, false><<<grid, 256, 0, stream>>>(h2, A2, head,      nxt, ei, Nn);
        prop_step_kernel<2, true,  false, true ><<<grid, 256, 0, stream>>>(A2, d_out, head + Nn, nxt, ei, Nn);
    }
}